// Round 2
// baseline (157.524 us; speedup 1.0000x reference)
//
#include <hip/hip_runtime.h>
#include <hip/hip_bf16.h>

// SupervisedGraphSage forward. Device buffers are fp32 (per reference dtypes);
// internal compute in bf16 MFMA with fp32 accumulation (threshold is 2% of max|ref|).
//
// Algebraic restructure via linearity of mean-aggregation:
//   z  = x @ W1^T                       [N, D]   (K1, streams x once)
//   h1 = leaky((z[neigh1].sum + z)/6)   [N, D]   (K2, gather in D-domain, bf16)
//   h2 = leaky((h1[neigh2].sum + h1[nodes])/11 @ W2^T)  [B, D] (K3, fused)
//   out = h2 @ Wc^T                     [B, C]   (K4, fp32 out)

#define NN 100000
#define FF 512
#define DD 256
#define BB 16384
#define CC 40

typedef __attribute__((ext_vector_type(8))) short bf16x8;
typedef __attribute__((ext_vector_type(4))) float f32x4;
typedef unsigned short u16;
typedef unsigned int u32;

__device__ __forceinline__ float bf_lo(u32 u) { u32 v = u << 16; float f; __builtin_memcpy(&f, &v, 4); return f; }
__device__ __forceinline__ float bf_hi(u32 u) { u32 v = u & 0xffff0000u; float f; __builtin_memcpy(&f, &v, 4); return f; }
__device__ __forceinline__ float2 bf2f(u32 u) { return make_float2(bf_lo(u), bf_hi(u)); }
__device__ __forceinline__ u32 packbf2(float a, float b) {
  __hip_bfloat162 h = __float22bfloat162_rn(make_float2(a, b));
  u32 u; __builtin_memcpy(&u, &h, 4); return u;
}
__device__ __forceinline__ u16 fbits(float v) {
  __hip_bfloat16 h = __float2bfloat16(v);
  u16 u; __builtin_memcpy(&u, &h, 2); return u;
}
__device__ __forceinline__ float lrelu(float v) { return v >= 0.f ? v : 0.2f * v; }
// byte offset of 16B chunk c in row r of a [R][64]-bf16 LDS tile, XOR-swizzled
// so stride-128B column reads spread across banks (G4 fix).
__device__ __forceinline__ int swz(int r, int c) { return r * 128 + ((c ^ (r & 7)) << 4); }

// ---------------------------------------------------------------- K0
// Convert W1 (131072 f32), W2 (65536), Wc (10240) to bf16 once. 4 floats/thread.
__global__ __launch_bounds__(256) void k0_cvt(
    const float* __restrict__ W1, const float* __restrict__ W2, const float* __restrict__ Wc,
    u16* __restrict__ w1b, u16* __restrict__ w2b, u16* __restrict__ wcb)
{
  const int i = blockIdx.x * 256 + threadIdx.x;  // one float4 per thread, 51712 total
  const float* src; u16* dst; int off;
  if (i < 32768)      { src = W1; dst = w1b; off = i * 4; }
  else if (i < 49152) { src = W2; dst = w2b; off = (i - 32768) * 4; }
  else if (i < 51712) { src = Wc; dst = wcb; off = (i - 49152) * 4; }
  else return;
  const float4 v = *(const float4*)(src + off);
  uint2 o; o.x = packbf2(v.x, v.y); o.y = packbf2(v.z, v.w);
  *(uint2*)(dst + off) = o;
}

// ---------------------------------------------------------------- K1
// z = x @ W1^T (no activation). BM=128, BN=256, BK=64, 512 thr = 8 waves (2x4).
// A staged from fp32 x with inline cvt->bf16; B from pre-converted bf16 W1.
__global__ __launch_bounds__(512) void k1_gemm(
    const float* __restrict__ x, const u16* __restrict__ w1b, u16* __restrict__ z)
{
  __shared__ __align__(16) unsigned char lds[49152];  // A 16KB @0, B 32KB @16384

  const int t = threadIdx.x;
  const int rowBase = blockIdx.x * 128;
  const int lane = t & 63, w = t >> 6;
  const int wm = w >> 2, wn = w & 3;
  const int lr = lane & 15, kg = lane >> 4;

  u32 offA[2]; int aW[2];
#pragma unroll
  for (int i = 0; i < 2; ++i) {
    const int id = t + i * 512;
    const int r = id >> 3, c = id & 7;
    int row = rowBase + r; if (row > NN - 1) row = NN - 1;   // pad rows read row 99999
    offA[i] = (u32)row * FF + c * 8;
    aW[i] = swz(r, c);
  }
  u32 offB[4]; int bW[4];
#pragma unroll
  for (int i = 0; i < 4; ++i) {
    const int id = t + i * 512;
    const int r = id >> 3, c = id & 7;   // r in [0,256)
    offB[i] = (u32)r * FF + c * 8;
    bW[i] = 16384 + swz(r, c);
  }
  int aA[2][4], bA[2][4];
#pragma unroll
  for (int kk = 0; kk < 2; ++kk) {
    const int cb = kk * 4 + kg;
#pragma unroll
    for (int m = 0; m < 4; ++m) aA[kk][m] = swz(wm * 64 + m * 16 + lr, cb);
#pragma unroll
    for (int n = 0; n < 4; ++n) bA[kk][n] = 16384 + swz(wn * 64 + n * 16 + lr, cb);
  }

  f32x4 acc[4][4];
#pragma unroll
  for (int m = 0; m < 4; ++m)
#pragma unroll
    for (int n = 0; n < 4; ++n) acc[m][n] = (f32x4)0.0f;

  for (int ks = 0; ks < 8; ++ks) {
    __syncthreads();
#pragma unroll
    for (int i = 0; i < 2; ++i) {
      const float4 v0 = *(const float4*)(x + offA[i] + ks * 64);
      const float4 v1 = *(const float4*)(x + offA[i] + ks * 64 + 4);
      uint4 o;
      o.x = packbf2(v0.x, v0.y); o.y = packbf2(v0.z, v0.w);
      o.z = packbf2(v1.x, v1.y); o.w = packbf2(v1.z, v1.w);
      *(uint4*)(lds + aW[i]) = o;
    }
#pragma unroll
    for (int i = 0; i < 4; ++i)
      *(uint4*)(lds + bW[i]) = *(const uint4*)(w1b + offB[i] + ks * 64);
    __syncthreads();
#pragma unroll
    for (int kk = 0; kk < 2; ++kk) {
      bf16x8 av[4], bv[4];
#pragma unroll
      for (int m = 0; m < 4; ++m) av[m] = *(const bf16x8*)(lds + aA[kk][m]);
#pragma unroll
      for (int n = 0; n < 4; ++n) bv[n] = *(const bf16x8*)(lds + bA[kk][n]);
#pragma unroll
      for (int m = 0; m < 4; ++m)
#pragma unroll
        for (int n = 0; n < 4; ++n)
          acc[m][n] = __builtin_amdgcn_mfma_f32_16x16x32_bf16(av[m], bv[n], acc[m][n], 0, 0, 0);
    }
  }
  // C/D map: col=lane&15, row=(lane>>4)*4+j. z padded to 100096 rows -> no guard.
#pragma unroll
  for (int m = 0; m < 4; ++m) {
    const int r0 = rowBase + wm * 64 + m * 16 + kg * 4;
#pragma unroll
    for (int j = 0; j < 4; ++j)
#pragma unroll
      for (int n = 0; n < 4; ++n)
        z[(u32)(r0 + j) * DD + wn * 64 + n * 16 + lr] = fbits(acc[m][n][j]);
  }
}

// ---------------------------------------------------------------- K2
// h1 = leaky((z[neigh1].sum + z)/6). 8 rows/block, 32 lanes/row, uint4 chunks.
__global__ __launch_bounds__(256) void k2_agg1(
    const u16* __restrict__ z, const int* __restrict__ neigh1, u16* __restrict__ h1)
{
  const int t = threadIdx.x;
  const int row = blockIdx.x * 8 + (t >> 5);   // grid 12500*8 = 100000 exact
  const int ch = t & 31;
  const u32 o0 = (u32)row * DD + ch * 8;
  uint4 a = *(const uint4*)(z + o0);
  float2 s0 = bf2f(a.x), s1 = bf2f(a.y), s2 = bf2f(a.z), s3 = bf2f(a.w);
#pragma unroll
  for (int j = 0; j < 5; ++j) {
    const int idx = neigh1[row * 5 + j];
    const uint4 v = *(const uint4*)(z + (u32)idx * DD + ch * 8);
    s0.x += bf_lo(v.x); s0.y += bf_hi(v.x);
    s1.x += bf_lo(v.y); s1.y += bf_hi(v.y);
    s2.x += bf_lo(v.z); s2.y += bf_hi(v.z);
    s3.x += bf_lo(v.w); s3.y += bf_hi(v.w);
  }
  const float sc = 1.0f / 6.0f;
  uint4 o;
  o.x = packbf2(lrelu(s0.x * sc), lrelu(s0.y * sc));
  o.y = packbf2(lrelu(s1.x * sc), lrelu(s1.y * sc));
  o.z = packbf2(lrelu(s2.x * sc), lrelu(s2.y * sc));
  o.w = packbf2(lrelu(s3.x * sc), lrelu(s3.y * sc));
  *(uint4*)(h1 + o0) = o;
}

// ---------------------------------------------------------------- K3
// h2 = leaky((h1[neigh2].sum + h1[nodes])/11 @ W2^T). BM=64, BN=256, BK=64,
// 256 thr = 4 waves (1x4), wave tile 64x64. A staged via 11-way gather-sum.
__global__ __launch_bounds__(256) void k3_agg_gemm(
    const u16* __restrict__ h1, const u16* __restrict__ w2b,
    const int* __restrict__ nodes, const int* __restrict__ neigh2,
    u16* __restrict__ h2)
{
  __shared__ __align__(16) unsigned char lds[8192 + 32768];  // A 8KB, B 32KB

  const int t = threadIdx.x;
  const int rowBase = blockIdx.x * 64;  // 256 blocks * 64 = 16384 exact
  const int lane = t & 63, w = t >> 6;  // w = wn
  const int lr = lane & 15, kg = lane >> 4;

  u32 offA[2][11]; int aW[2];
#pragma unroll
  for (int i = 0; i < 2; ++i) {
    const int id = t + i * 256;
    const int r = id >> 3, c = id & 7;
    const int b = rowBase + r;
    offA[i][0] = (u32)nodes[b] * DD + c * 8;
#pragma unroll
    for (int j = 0; j < 10; ++j)
      offA[i][1 + j] = (u32)neigh2[b * 10 + j] * DD + c * 8;
    aW[i] = swz(r, c);
  }
  u32 offB[8]; int bW[8];
#pragma unroll
  for (int i = 0; i < 8; ++i) {
    const int id = t + i * 256;
    const int r = id >> 3, c = id & 7;
    offB[i] = (u32)r * DD + c * 8;
    bW[i] = 8192 + swz(r, c);
  }
  int aA[2][4], bA[2][4];
#pragma unroll
  for (int kk = 0; kk < 2; ++kk) {
    const int cb = kk * 4 + kg;
#pragma unroll
    for (int m = 0; m < 4; ++m) aA[kk][m] = swz(m * 16 + lr, cb);
#pragma unroll
    for (int n = 0; n < 4; ++n) bA[kk][n] = 8192 + swz(w * 64 + n * 16 + lr, cb);
  }

  f32x4 acc[4][4];
#pragma unroll
  for (int m = 0; m < 4; ++m)
#pragma unroll
    for (int n = 0; n < 4; ++n) acc[m][n] = (f32x4)0.0f;

  for (int ks = 0; ks < 4; ++ks) {
    __syncthreads();
#pragma unroll
    for (int i = 0; i < 2; ++i) {
      float2 s0 = make_float2(0.f, 0.f), s1 = make_float2(0.f, 0.f);
      float2 s2 = make_float2(0.f, 0.f), s3 = make_float2(0.f, 0.f);
#pragma unroll
      for (int j = 0; j < 11; ++j) {
        const uint4 v = *(const uint4*)(h1 + offA[i][j] + ks * 64);
        s0.x += bf_lo(v.x); s0.y += bf_hi(v.x);
        s1.x += bf_lo(v.y); s1.y += bf_hi(v.y);
        s2.x += bf_lo(v.z); s2.y += bf_hi(v.z);
        s3.x += bf_lo(v.w); s3.y += bf_hi(v.w);
      }
      const float sc = 1.0f / 11.0f;
      uint4 o;
      o.x = packbf2(s0.x * sc, s0.y * sc);
      o.y = packbf2(s1.x * sc, s1.y * sc);
      o.z = packbf2(s2.x * sc, s2.y * sc);
      o.w = packbf2(s3.x * sc, s3.y * sc);
      *(uint4*)(lds + aW[i]) = o;
    }
#pragma unroll
    for (int i = 0; i < 8; ++i)
      *(uint4*)(lds + bW[i]) = *(const uint4*)(w2b + offB[i] + ks * 64);
    __syncthreads();
#pragma unroll
    for (int kk = 0; kk < 2; ++kk) {
      bf16x8 av[4], bv[4];
#pragma unroll
      for (int m = 0; m < 4; ++m) av[m] = *(const bf16x8*)(lds + aA[kk][m]);
#pragma unroll
      for (int n = 0; n < 4; ++n) bv[n] = *(const bf16x8*)(lds + bA[kk][n]);
#pragma unroll
      for (int m = 0; m < 4; ++m)
#pragma unroll
        for (int n = 0; n < 4; ++n)
          acc[m][n] = __builtin_amdgcn_mfma_f32_16x16x32_bf16(av[m], bv[n], acc[m][n], 0, 0, 0);
    }
  }
#pragma unroll
  for (int m = 0; m < 4; ++m) {
    const int r0 = rowBase + m * 16 + kg * 4;
#pragma unroll
    for (int j = 0; j < 4; ++j)
#pragma unroll
      for (int n = 0; n < 4; ++n)
        h2[(u32)(r0 + j) * DD + w * 64 + n * 16 + lr] = fbits(lrelu(acc[m][n][j]));
  }
}

// ---------------------------------------------------------------- K4
// out = h2 @ Wc^T (fp32 out). BM=64, N=48 cols staged (40 valid), K=256.
// 256 thr = 4 waves; wave tile 16x48.
__global__ __launch_bounds__(256) void k4_scores(
    const u16* __restrict__ h2, const u16* __restrict__ wcb, float* __restrict__ out)
{
  __shared__ __align__(16) unsigned char lds[8192 + 6144];  // A 8KB, B 6KB (48 rows)

  const int t = threadIdx.x;
  const int rowBase = blockIdx.x * 64;
  const int lane = t & 63, w = t >> 6;
  const int lr = lane & 15, kg = lane >> 4;

  u32 offA[2]; int aW[2];
#pragma unroll
  for (int i = 0; i < 2; ++i) {
    const int id = t + i * 256;
    const int r = id >> 3, c = id & 7;
    offA[i] = (u32)(rowBase + r) * DD + c * 8;
    aW[i] = swz(r, c);
  }
  // B: 48 rows x 8 chunks = 384 chunk-writes -> 2 iterations over 256 threads.
  u32 offBc[2]; int bWr[2]; int bValid[2]; int bRow[2];
#pragma unroll
  for (int i = 0; i < 2; ++i) {
    const int id = t + i * 256;
    const int r = id >> 3, c = id & 7;
    bValid[i] = (id < 384);
    bRow[i] = r;
    offBc[i] = (u32)r * DD + c * 8;
    bWr[i] = 8192 + swz(r, c);
  }

  int aA[2], bA[2][3];
#pragma unroll
  for (int kk = 0; kk < 2; ++kk) {
    const int cb = kk * 4 + kg;
    aA[kk] = swz(w * 16 + lr, cb);
#pragma unroll
    for (int n = 0; n < 3; ++n) bA[kk][n] = 8192 + swz(n * 16 + lr, cb);
  }

  f32x4 acc[3];
#pragma unroll
  for (int n = 0; n < 3; ++n) acc[n] = (f32x4)0.0f;

  for (int ks = 0; ks < 4; ++ks) {
    __syncthreads();
#pragma unroll
    for (int i = 0; i < 2; ++i)
      *(uint4*)(lds + aW[i]) = *(const uint4*)(h2 + offA[i] + ks * 64);
#pragma unroll
    for (int i = 0; i < 2; ++i) {
      if (bValid[i]) {
        uint4 v = make_uint4(0u, 0u, 0u, 0u);
        if (bRow[i] < CC) v = *(const uint4*)(wcb + offBc[i] + ks * 64);
        *(uint4*)(lds + bWr[i]) = v;
      }
    }
    __syncthreads();
#pragma unroll
    for (int kk = 0; kk < 2; ++kk) {
      const bf16x8 a = *(const bf16x8*)(lds + aA[kk]);
#pragma unroll
      for (int n = 0; n < 3; ++n) {
        const bf16x8 b = *(const bf16x8*)(lds + bA[kk][n]);
        acc[n] = __builtin_amdgcn_mfma_f32_16x16x32_bf16(a, b, acc[n], 0, 0, 0);
      }
    }
  }
#pragma unroll
  for (int n = 0; n < 3; ++n) {
    const int col = n * 16 + lr;
    if (col < CC) {
#pragma unroll
      for (int j = 0; j < 4; ++j) {
        const int r = rowBase + w * 16 + kg * 4 + j;
        out[(u32)r * CC + col] = acc[n][j];
      }
    }
  }
}

extern "C" void kernel_launch(void* const* d_in, const int* in_sizes, int n_in,
                              void* d_out, int out_size, void* d_ws, size_t ws_size,
                              hipStream_t stream) {
  const float* x      = (const float*)d_in[0];
  const float* W1     = (const float*)d_in[1];
  const float* W2     = (const float*)d_in[2];
  const float* Wc     = (const float*)d_in[3];
  const int* nodes    = (const int*)d_in[4];
  const int* neigh1   = (const int*)d_in[5];
  const int* neigh2   = (const int*)d_in[6];

  // ws layout (bf16 elements)
  u16* z   = (u16*)d_ws;                       // 100096*256 = 51.25 MB
  u16* h1  = z  + (size_t)100096 * 256;        // 51.25 MB
  u16* h2  = h1 + (size_t)100096 * 256;        // 16384*256 = 8.39 MB
  u16* w1b = h2 + (size_t)16384 * 256;         // 256 KB
  u16* w2b = w1b + (size_t)256 * 512;          // 128 KB
  u16* wcb = w2b + (size_t)256 * 256;          // 20 KB   (total ~111.3 MB)

  k0_cvt<<<dim3(202), dim3(256), 0, stream>>>(W1, W2, Wc, w1b, w2b, wcb);
  k1_gemm<<<dim3(782), dim3(512), 0, stream>>>(x, w1b, z);
  k2_agg1<<<dim3(12500), dim3(256), 0, stream>>>(z, neigh1, h1);
  k3_agg_gemm<<<dim3(256), dim3(256), 0, stream>>>(h1, w2b, nodes, neigh2, h2);
  k4_scores<<<dim3(256), dim3(256), 0, stream>>>(h2, wcb, (float*)d_out);
}

// Round 3
// 154.469 us; speedup vs baseline: 1.0198x; 1.0198x over previous
//
#include <hip/hip_runtime.h>
#include <hip/hip_bf16.h>

// SupervisedGraphSage forward. fp32 device buffers; bf16 MFMA internally.
//   z  = x @ W1^T                        [N, D]  (K1)
//   h1 = leaky((z[neigh1].sum + z)/6)    [N, D]  (K2)
//   h2 = leaky((h1[neigh2].sum+h1[nodes])/11 @ W2^T); out = h2 @ Wc^T  (K3 fused)
// Weights pre-converted to bf16 with chunk-swizzled storage (K0) so that
// linear global_load_lds staging yields the XOR-swizzled LDS layout (m173).

#define NN 100000
#define FF 512
#define DD 256
#define BB 16384
#define CC 40

typedef __attribute__((ext_vector_type(8))) short bf16x8;
typedef __attribute__((ext_vector_type(4))) float f32x4;
typedef unsigned short u16;
typedef unsigned int u32;

__device__ __forceinline__ float bf_lo(u32 u) { u32 v = u << 16; float f; __builtin_memcpy(&f, &v, 4); return f; }
__device__ __forceinline__ float bf_hi(u32 u) { u32 v = u & 0xffff0000u; float f; __builtin_memcpy(&f, &v, 4); return f; }
__device__ __forceinline__ float2 bf2f(u32 u) { return make_float2(bf_lo(u), bf_hi(u)); }
__device__ __forceinline__ u32 packbf2(float a, float b) {
  __hip_bfloat162 h = __float22bfloat162_rn(make_float2(a, b));
  u32 u; __builtin_memcpy(&u, &h, 4); return u;
}
__device__ __forceinline__ u16 fbits(float v) {
  __hip_bfloat16 h = __float2bfloat16(v);
  u16 u; __builtin_memcpy(&u, &h, 2); return u;
}
__device__ __forceinline__ float lrelu(float v) { return v >= 0.f ? v : 0.2f * v; }
// [R][64]-bf16 tile: byte offset of chunk c in row r, XOR-swizzled (G4).
__device__ __forceinline__ int swz(int r, int c) { return r * 128 + ((c ^ (r & 7)) << 4); }
// direct global->LDS 16B copy (dest = wave-uniform base + lane*16)
__device__ __forceinline__ void gld_lds16(const u16* g, void* l) {
  __builtin_amdgcn_global_load_lds((const __attribute__((address_space(1))) unsigned int*)g,
                                   (__attribute__((address_space(3))) unsigned int*)l, 16, 0, 0);
}

// ---------------------------------------------------------------- K0
// fp32 weights -> bf16, stored chunk-swizzled: dst chunk (r, g*8+cp) holds
// logical chunk (r, g*8 + (cp ^ (r&7))). One 16B dst chunk per thread.
__global__ __launch_bounds__(256) void k0_cvt(
    const float* __restrict__ W1, const float* __restrict__ W2, const float* __restrict__ Wc,
    u16* __restrict__ w1b, u16* __restrict__ w2b, u16* __restrict__ wcb)
{
  const int i = blockIdx.x * 256 + threadIdx.x;
  const float* src; u16* dst; int r, cc, rowE;
  if (i < 16384)      { src = W1; dst = w1b; r = i >> 6; cc = i & 63; rowE = 512; }
  else if (i < 24576) { int j = i - 16384; src = W2; dst = w2b; r = j >> 5; cc = j & 31; rowE = 256; }
  else if (i < 25856) { int j = i - 24576; src = Wc; dst = wcb; r = j >> 5; cc = j & 31; rowE = 256; }
  else return;
  const int g = cc >> 3, cp = cc & 7;
  const float* s = src + (u32)r * rowE + g * 64 + (u32)(cp ^ (r & 7)) * 8;
  const float4 v0 = *(const float4*)s;
  const float4 v1 = *(const float4*)(s + 4);
  uint4 o;
  o.x = packbf2(v0.x, v0.y); o.y = packbf2(v0.z, v0.w);
  o.z = packbf2(v1.x, v1.y); o.w = packbf2(v1.z, v1.w);
  *(uint4*)(dst + (u32)r * rowE + g * 64 + cp * 8) = o;
}

// ---------------------------------------------------------------- K1
// z = x @ W1^T. BM=128, BN=256, BK=64, 512 thr = 8 waves (2Mx4N), wave 64x64.
// A: fp32->bf16 reg-staged, issue-early (T14). B: global_load_lds, pre-swizzled.
__global__ __launch_bounds__(512, 4) void k1_gemm(
    const float* __restrict__ x, const u16* __restrict__ w1b, u16* __restrict__ z)
{
  __shared__ __align__(16) unsigned char lds[49152];  // A 16KB @0, B 32KB @16384

  const int t = threadIdx.x;
  const int rowBase = blockIdx.x * 128;
  const int lane = t & 63, w = t >> 6;
  const int wm = w >> 2, wn = w & 3;
  const int lr = lane & 15, kg = lane >> 4;

  u32 offA[2]; int aW[2];
#pragma unroll
  for (int i = 0; i < 2; ++i) {
    const int id = t + i * 512;
    const int r = id >> 3, c = id & 7;
    int row = rowBase + r; if (row > NN - 1) row = NN - 1;
    offA[i] = (u32)row * FF + c * 8;
    aW[i] = swz(r, c);
  }
  // B: issue i covers rows w*8 + i*64 + (lane>>3), chunk lane&7
  const u32 bofs = (u32)(w * 8 + (lane >> 3)) * FF + (u32)(lane & 7) * 8;
  unsigned char* bl0 = lds + 16384 + w * 1024;

  int aA[2][4], bA[2][4];
#pragma unroll
  for (int kk = 0; kk < 2; ++kk) {
    const int cb = kk * 4 + kg;
#pragma unroll
    for (int m = 0; m < 4; ++m) aA[kk][m] = swz(wm * 64 + m * 16 + lr, cb);
#pragma unroll
    for (int n = 0; n < 4; ++n) bA[kk][n] = 16384 + swz(wn * 64 + n * 16 + lr, cb);
  }

  f32x4 acc[4][4];
#pragma unroll
  for (int m = 0; m < 4; ++m)
#pragma unroll
    for (int n = 0; n < 4; ++n) acc[m][n] = (f32x4)0.0f;

  float4 pa[2][2];
#pragma unroll
  for (int i = 0; i < 2; ++i) {
    pa[i][0] = *(const float4*)(x + offA[i]);
    pa[i][1] = *(const float4*)(x + offA[i] + 4);
  }

  for (int ks = 0; ks < 8; ++ks) {
    if (ks) __builtin_amdgcn_s_barrier();   // raw: A-prefetch stays in flight
#pragma unroll
    for (int i = 0; i < 2; ++i) {
      uint4 o;
      o.x = packbf2(pa[i][0].x, pa[i][0].y); o.y = packbf2(pa[i][0].z, pa[i][0].w);
      o.z = packbf2(pa[i][1].x, pa[i][1].y); o.w = packbf2(pa[i][1].z, pa[i][1].w);
      *(uint4*)(lds + aW[i]) = o;
    }
#pragma unroll
    for (int i = 0; i < 4; ++i)
      gld_lds16(w1b + bofs + (u32)i * 64 * FF + (u32)ks * 64, bl0 + i * 8192);
    __syncthreads();                         // drains vmcnt(0): B landed, A writes done
    if (ks < 7) {
#pragma unroll
      for (int i = 0; i < 2; ++i) {          // T14 issue-early for next K-step
        pa[i][0] = *(const float4*)(x + offA[i] + (u32)(ks + 1) * 64);
        pa[i][1] = *(const float4*)(x + offA[i] + (u32)(ks + 1) * 64 + 4);
      }
    }
    __builtin_amdgcn_sched_barrier(0);       // keep prefetch above MFMA phase
#pragma unroll
    for (int kk = 0; kk < 2; ++kk) {
      bf16x8 av[4], bv[4];
#pragma unroll
      for (int m = 0; m < 4; ++m) av[m] = *(const bf16x8*)(lds + aA[kk][m]);
#pragma unroll
      for (int n = 0; n < 4; ++n) bv[n] = *(const bf16x8*)(lds + bA[kk][n]);
#pragma unroll
      for (int m = 0; m < 4; ++m)
#pragma unroll
        for (int n = 0; n < 4; ++n)
          acc[m][n] = __builtin_amdgcn_mfma_f32_16x16x32_bf16(av[m], bv[n], acc[m][n], 0, 0, 0);
    }
  }
#pragma unroll
  for (int m = 0; m < 4; ++m) {
    const int r0 = rowBase + wm * 64 + m * 16 + kg * 4;
#pragma unroll
    for (int j = 0; j < 4; ++j)
#pragma unroll
      for (int n = 0; n < 4; ++n)
        z[(u32)(r0 + j) * DD + wn * 64 + n * 16 + lr] = fbits(acc[m][n][j]);
  }
}

// ---------------------------------------------------------------- K2
// h1 = leaky((z[neigh1].sum + z)/6). 8 rows/block, 32 lanes/row.
__global__ __launch_bounds__(256) void k2_agg1(
    const u16* __restrict__ z, const int* __restrict__ neigh1, u16* __restrict__ h1)
{
  const int t = threadIdx.x;
  const int row = blockIdx.x * 8 + (t >> 5);
  const int ch = t & 31;
  const u32 o0 = (u32)row * DD + ch * 8;
  uint4 a = *(const uint4*)(z + o0);
  float2 s0 = bf2f(a.x), s1 = bf2f(a.y), s2 = bf2f(a.z), s3 = bf2f(a.w);
#pragma unroll
  for (int j = 0; j < 5; ++j) {
    const int idx = neigh1[row * 5 + j];
    const uint4 v = *(const uint4*)(z + (u32)idx * DD + ch * 8);
    s0.x += bf_lo(v.x); s0.y += bf_hi(v.x);
    s1.x += bf_lo(v.y); s1.y += bf_hi(v.y);
    s2.x += bf_lo(v.z); s2.y += bf_hi(v.z);
    s3.x += bf_lo(v.w); s3.y += bf_hi(v.w);
  }
  const float sc = 1.0f / 6.0f;
  uint4 o;
  o.x = packbf2(lrelu(s0.x * sc), lrelu(s0.y * sc));
  o.y = packbf2(lrelu(s1.x * sc), lrelu(s1.y * sc));
  o.z = packbf2(lrelu(s2.x * sc), lrelu(s2.y * sc));
  o.w = packbf2(lrelu(s3.x * sc), lrelu(s3.y * sc));
  *(uint4*)(h1 + o0) = o;
}

// ---------------------------------------------------------------- K3 (fused K3+K4)
// h2tile = leaky(agg2 @ W2^T) kept in LDS; out = h2tile @ Wc^T.
// BM=64, BN=256, BK=64, 512 thr = 8 waves (2Mx4N), wave 32x64.
__global__ __launch_bounds__(512, 2) void k3_fused(
    const u16* __restrict__ h1, const u16* __restrict__ w2b, const u16* __restrict__ wcb,
    const int* __restrict__ nodes, const int* __restrict__ neigh2, float* __restrict__ out)
{
  // 0: A 8KB | 8192: B 32KB | 40960: Wc 24KB. After loop: 0..32KB = h2 tile.
  __shared__ __align__(16) unsigned char lds[65536];

  const int t = threadIdx.x;
  const int rowBase = blockIdx.x * 64;
  const int lane = t & 63, w = t >> 6;
  const int wm = w >> 2, wn = w & 3;
  const int lr = lane & 15, kg = lane >> 4;

  // Wc -> LDS once (pre-swizzled storage => linear copy). 48 rows (8 zero-pad).
#pragma unroll
  for (int i = 0; i < 3; ++i) {
    const int id = t + i * 512;
    uint4 v = make_uint4(0u, 0u, 0u, 0u);
    if (id < 1280) v = *(const uint4*)(wcb + (u32)id * 8);
    *(uint4*)(lds + 40960 + id * 16) = v;
  }

  // A gather: 1 chunk-task/thread (64 rows x 8 chunks), 11-way gather.
  const int r = t >> 3, c = t & 7;
  const int b = rowBase + r;
  u32 offA[11];
  offA[0] = (u32)nodes[b] * DD + (u32)c * 8;
#pragma unroll
  for (int j = 0; j < 10; ++j)
    offA[1 + j] = (u32)neigh2[b * 10 + j] * DD + (u32)c * 8;
  const int aW = swz(r, c);

  const u32 bofs = (u32)(w * 8 + (lane >> 3)) * DD + (u32)(lane & 7) * 8;
  unsigned char* bl0 = lds + 8192 + w * 1024;

  int aA[2][2], bA[2][4];
#pragma unroll
  for (int kk = 0; kk < 2; ++kk) {
    const int cb = kk * 4 + kg;
#pragma unroll
    for (int m = 0; m < 2; ++m) aA[kk][m] = swz(wm * 32 + m * 16 + lr, cb);
#pragma unroll
    for (int n = 0; n < 4; ++n) bA[kk][n] = 8192 + swz(wn * 64 + n * 16 + lr, cb);
  }

  f32x4 acc[2][4];
#pragma unroll
  for (int m = 0; m < 2; ++m)
#pragma unroll
    for (int n = 0; n < 4; ++n) acc[m][n] = (f32x4)0.0f;

  uint4 ag[11];
#pragma unroll
  for (int j = 0; j < 11; ++j) ag[j] = *(const uint4*)(h1 + offA[j]);

  for (int ks = 0; ks < 4; ++ks) {
    if (ks) __builtin_amdgcn_s_barrier();
    {
      float2 s0 = make_float2(0.f, 0.f), s1 = make_float2(0.f, 0.f);
      float2 s2 = make_float2(0.f, 0.f), s3 = make_float2(0.f, 0.f);
#pragma unroll
      for (int j = 0; j < 11; ++j) {
        s0.x += bf_lo(ag[j].x); s0.y += bf_hi(ag[j].x);
        s1.x += bf_lo(ag[j].y); s1.y += bf_hi(ag[j].y);
        s2.x += bf_lo(ag[j].z); s2.y += bf_hi(ag[j].z);
        s3.x += bf_lo(ag[j].w); s3.y += bf_hi(ag[j].w);
      }
      const float sc = 1.0f / 11.0f;
      uint4 o;
      o.x = packbf2(s0.x * sc, s0.y * sc);
      o.y = packbf2(s1.x * sc, s1.y * sc);
      o.z = packbf2(s2.x * sc, s2.y * sc);
      o.w = packbf2(s3.x * sc, s3.y * sc);
      *(uint4*)(lds + aW) = o;
    }
#pragma unroll
    for (int i = 0; i < 4; ++i)
      gld_lds16(w2b + bofs + (u32)i * 64 * DD + (u32)ks * 64, bl0 + i * 8192);
    __syncthreads();
    if (ks < 3) {
#pragma unroll
      for (int j = 0; j < 11; ++j)
        ag[j] = *(const uint4*)(h1 + offA[j] + (u32)(ks + 1) * 64);
    }
    __builtin_amdgcn_sched_barrier(0);
#pragma unroll
    for (int kk = 0; kk < 2; ++kk) {
      bf16x8 av[2], bv[4];
#pragma unroll
      for (int m = 0; m < 2; ++m) av[m] = *(const bf16x8*)(lds + aA[kk][m]);
#pragma unroll
      for (int n = 0; n < 4; ++n) bv[n] = *(const bf16x8*)(lds + bA[kk][n]);
#pragma unroll
      for (int m = 0; m < 2; ++m)
#pragma unroll
        for (int n = 0; n < 4; ++n)
          acc[m][n] = __builtin_amdgcn_mfma_f32_16x16x32_bf16(av[m], bv[n], acc[m][n], 0, 0, 0);
    }
  }

  __syncthreads();  // all waves done reading A/B before h2tile overwrites them
  // h2 tile -> LDS [64][256] bf16, swizzle: chunk low-3 bits ^= row&7
#pragma unroll
  for (int m = 0; m < 2; ++m) {
#pragma unroll
    for (int j = 0; j < 4; ++j) {
      const int row = wm * 32 + m * 16 + kg * 4 + j;
#pragma unroll
      for (int n = 0; n < 4; ++n) {
        const int col = wn * 64 + n * 16 + lr;
        const int ch = col >> 3;
        const int pch = (ch & 24) | ((ch ^ row) & 7);
        *(u16*)(lds + row * 512 + pch * 16 + (col & 7) * 2) = fbits(lrelu(acc[m][n][j]));
      }
    }
  }
  __syncthreads();

  if (w < 4) {  // scores: wave w -> output rows w*16..+15, 48 cols (40 valid)
    f32x4 acc2[3];
#pragma unroll
    for (int n = 0; n < 3; ++n) acc2[n] = (f32x4)0.0f;
    const int arow = w * 16 + lr;
#pragma unroll
    for (int ks2 = 0; ks2 < 8; ++ks2) {
      const int chb = ks2 * 4 + kg;
      const int pchA = (chb & 24) | ((chb ^ arow) & 7);
      const bf16x8 a = *(const bf16x8*)(lds + arow * 512 + pchA * 16);
#pragma unroll
      for (int n = 0; n < 3; ++n) {
        const int brow = n * 16 + lr;
        const int pchB = (chb & 24) | ((chb ^ brow) & 7);
        const bf16x8 bb = *(const bf16x8*)(lds + 40960 + brow * 512 + pchB * 16);
        acc2[n] = __builtin_amdgcn_mfma_f32_16x16x32_bf16(a, bb, acc2[n], 0, 0, 0);
      }
    }
#pragma unroll
    for (int n = 0; n < 3; ++n) {
      const int col = n * 16 + lr;
      if (col < CC) {
#pragma unroll
        for (int j = 0; j < 4; ++j) {
          const int rr = rowBase + w * 16 + kg * 4 + j;
          out[(u32)rr * CC + col] = acc2[n][j];
        }
      }
    }
  }
}

extern "C" void kernel_launch(void* const* d_in, const int* in_sizes, int n_in,
                              void* d_out, int out_size, void* d_ws, size_t ws_size,
                              hipStream_t stream) {
  const float* x    = (const float*)d_in[0];
  const float* W1   = (const float*)d_in[1];
  const float* W2   = (const float*)d_in[2];
  const float* Wc   = (const float*)d_in[3];
  const int* nodes  = (const int*)d_in[4];
  const int* neigh1 = (const int*)d_in[5];
  const int* neigh2 = (const int*)d_in[6];

  u16* z   = (u16*)d_ws;                     // 100096*256 bf16
  u16* h1  = z + (size_t)100096 * 256;       // 100096*256 bf16
  u16* w1b = h1 + (size_t)100096 * 256;      // 256x512 bf16 (chunk-swizzled)
  u16* w2b = w1b + (size_t)256 * 512;        // 256x256 bf16 (chunk-swizzled)
  u16* wcb = w2b + (size_t)256 * 256;        // 40x256 bf16 (chunk-swizzled)

  k0_cvt<<<dim3(101), dim3(256), 0, stream>>>(W1, W2, Wc, w1b, w2b, wcb);
  k1_gemm<<<dim3(782), dim3(512), 0, stream>>>(x, w1b, z);
  k2_agg1<<<dim3(12500), dim3(256), 0, stream>>>(z, neigh1, h1);
  k3_fused<<<dim3(256), dim3(512), 0, stream>>>(h1, w2b, wcb, nodes, neigh2, (float*)d_out);
}

// Round 4
// 152.080 us; speedup vs baseline: 1.0358x; 1.0157x over previous
//
#include <hip/hip_runtime.h>
#include <hip/hip_bf16.h>

// SupervisedGraphSage forward. fp32 device buffers; bf16 MFMA internally.
//   z  = x @ W1^T                        [N, D]  (K1)
//   h1 = leaky((z[neigh1].sum + z)/6)    [N, D]  (K2)
//   h2 = leaky((h1[neigh2].sum+h1[nodes])/11 @ W2^T); out = h2 @ Wc^T  (K3 fused)
// K1: B double-buffered with counted vmcnt (loads stay in flight across
// barriers); epilogue uses swapped-operand MFMA so stores are 8B-contiguous.

#define NN 100000
#define FF 512
#define DD 256
#define BB 16384
#define CC 40

typedef __attribute__((ext_vector_type(8))) short bf16x8;
typedef __attribute__((ext_vector_type(4))) float f32x4;
typedef unsigned short u16;
typedef unsigned int u32;

__device__ __forceinline__ float bf_lo(u32 u) { u32 v = u << 16; float f; __builtin_memcpy(&f, &v, 4); return f; }
__device__ __forceinline__ float bf_hi(u32 u) { u32 v = u & 0xffff0000u; float f; __builtin_memcpy(&f, &v, 4); return f; }
__device__ __forceinline__ float2 bf2f(u32 u) { return make_float2(bf_lo(u), bf_hi(u)); }
__device__ __forceinline__ u32 packbf2(float a, float b) {
  __hip_bfloat162 h = __float22bfloat162_rn(make_float2(a, b));
  u32 u; __builtin_memcpy(&u, &h, 4); return u;
}
__device__ __forceinline__ u16 fbits(float v) {
  __hip_bfloat16 h = __float2bfloat16(v);
  u16 u; __builtin_memcpy(&u, &h, 2); return u;
}
__device__ __forceinline__ float lrelu(float v) { return v >= 0.f ? v : 0.2f * v; }
// [R][64]-bf16 tile: byte offset of chunk c in row r, XOR-swizzled (G4).
__device__ __forceinline__ int swz(int r, int c) { return r * 128 + ((c ^ (r & 7)) << 4); }
// direct global->LDS 16B copy (dest = wave-uniform base + lane*16)
__device__ __forceinline__ void gld_lds16(const u16* g, void* l) {
  __builtin_amdgcn_global_load_lds((const __attribute__((address_space(1))) unsigned int*)g,
                                   (__attribute__((address_space(3))) unsigned int*)l, 16, 0, 0);
}

// ---------------------------------------------------------------- K0
// fp32 weights -> bf16, stored chunk-swizzled: dst chunk (r, g*8+cp) holds
// logical chunk (r, g*8 + (cp ^ (r&7))). One 16B dst chunk per thread.
__global__ __launch_bounds__(256) void k0_cvt(
    const float* __restrict__ W1, const float* __restrict__ W2, const float* __restrict__ Wc,
    u16* __restrict__ w1b, u16* __restrict__ w2b, u16* __restrict__ wcb)
{
  const int i = blockIdx.x * 256 + threadIdx.x;
  const float* src; u16* dst; int r, cc, rowE;
  if (i < 16384)      { src = W1; dst = w1b; r = i >> 6; cc = i & 63; rowE = 512; }
  else if (i < 24576) { int j = i - 16384; src = W2; dst = w2b; r = j >> 5; cc = j & 31; rowE = 256; }
  else if (i < 25856) { int j = i - 24576; src = Wc; dst = wcb; r = j >> 5; cc = j & 31; rowE = 256; }
  else return;
  const int g = cc >> 3, cp = cc & 7;
  const float* s = src + (u32)r * rowE + g * 64 + (u32)(cp ^ (r & 7)) * 8;
  const float4 v0 = *(const float4*)s;
  const float4 v1 = *(const float4*)(s + 4);
  uint4 o;
  o.x = packbf2(v0.x, v0.y); o.y = packbf2(v0.z, v0.w);
  o.z = packbf2(v1.x, v1.y); o.w = packbf2(v1.z, v1.w);
  *(uint4*)(dst + (u32)r * rowE + g * 64 + cp * 8) = o;
}

// ---------------------------------------------------------------- K1
// z = x @ W1^T. BM=128, BN=256, BK=64, 512 thr = 8 waves (2Mx4N), wave 64x64.
// A: fp32->bf16 reg-staged (prefetched). B: global_load_lds into 2 LDS bufs,
// counted vmcnt(8) so next-step loads ride across the barrier.
__global__ __launch_bounds__(512, 4) void k1_gemm(
    const float* __restrict__ x, const u16* __restrict__ w1b, u16* __restrict__ z)
{
  __shared__ __align__(16) unsigned char lds[81920];  // A 16KB @0, B0 @16384, B1 @49152

  const int t = threadIdx.x;
  const int rowBase = blockIdx.x * 128;
  const int lane = t & 63, w = t >> 6;
  const int wm = w >> 2, wn = w & 3;
  const int lr = lane & 15, kg = lane >> 4;

  u32 offA[2]; int aW[2];
#pragma unroll
  for (int i = 0; i < 2; ++i) {
    const int id = t + i * 512;
    const int r = id >> 3, c = id & 7;
    int row = rowBase + r; if (row > NN - 1) row = NN - 1;
    offA[i] = (u32)row * FF + c * 8;
    aW[i] = swz(r, c);
  }
  // B: wave w covers rows w*8 + (lane>>3) + i*64, chunk lane&7 (pre-swizzled src)
  const u32 bofs = (u32)(w * 8 + (lane >> 3)) * FF + (u32)(lane & 7) * 8;

  int aA[2][4], bA[2][4];
#pragma unroll
  for (int kk = 0; kk < 2; ++kk) {
    const int cb = kk * 4 + kg;
#pragma unroll
    for (int m = 0; m < 4; ++m) aA[kk][m] = swz(wm * 64 + m * 16 + lr, cb);
#pragma unroll
    for (int n = 0; n < 4; ++n) bA[kk][n] = 16384 + swz(wn * 64 + n * 16 + lr, cb);
  }

  f32x4 acc[4][4];
#pragma unroll
  for (int m = 0; m < 4; ++m)
#pragma unroll
    for (int n = 0; n < 4; ++n) acc[m][n] = (f32x4)0.0f;

  // prologue: A[0] reg loads, then B[0] gld_lds -> buf0
  float4 pa[2][2];
#pragma unroll
  for (int i = 0; i < 2; ++i) {
    pa[i][0] = *(const float4*)(x + offA[i]);
    pa[i][1] = *(const float4*)(x + offA[i] + 4);
  }
#pragma unroll
  for (int i = 0; i < 4; ++i)
    gld_lds16(w1b + bofs + (u32)i * 64 * FF, lds + 16384 + w * 1024 + i * 8192);

#pragma unroll
  for (int ks = 0; ks < 8; ++ks) {
    if (ks) {
      __builtin_amdgcn_s_barrier();          // prev MFMA phase done; LDS reusable
      __builtin_amdgcn_sched_barrier(0);
    }
    // write A[ks] (compiler inserts vmcnt wait for pa; B[ks] may stay in flight)
#pragma unroll
    for (int i = 0; i < 2; ++i) {
      uint4 o;
      o.x = packbf2(pa[i][0].x, pa[i][0].y); o.y = packbf2(pa[i][0].z, pa[i][0].w);
      o.z = packbf2(pa[i][1].x, pa[i][1].y); o.w = packbf2(pa[i][1].z, pa[i][1].w);
      *(uint4*)(lds + aW[i]) = o;
    }
    if (ks < 7) {
      // issue A[ks+1] (4 loads) then B[ks+1] (4 gld_lds) -> 8 younger than B[ks]
#pragma unroll
      for (int i = 0; i < 2; ++i) {
        pa[i][0] = *(const float4*)(x + offA[i] + (u32)(ks + 1) * 64);
        pa[i][1] = *(const float4*)(x + offA[i] + (u32)(ks + 1) * 64 + 4);
      }
      unsigned char* bl = lds + 16384 + ((ks + 1) & 1) * 32768 + w * 1024;
#pragma unroll
      for (int i = 0; i < 4; ++i)
        gld_lds16(w1b + bofs + (u32)i * 64 * FF + (u32)(ks + 1) * 64, bl + i * 8192);
      asm volatile("s_waitcnt vmcnt(8) lgkmcnt(0)" ::: "memory");  // B[ks] landed
    } else {
      asm volatile("s_waitcnt vmcnt(0) lgkmcnt(0)" ::: "memory");
    }
    __builtin_amdgcn_sched_barrier(0);
    __builtin_amdgcn_s_barrier();
    __builtin_amdgcn_sched_barrier(0);
    const int bo = (ks & 1) * 32768;
#pragma unroll
    for (int kk = 0; kk < 2; ++kk) {
      bf16x8 av[4], bv[4];
#pragma unroll
      for (int m = 0; m < 4; ++m) av[m] = *(const bf16x8*)(lds + aA[kk][m]);
#pragma unroll
      for (int n = 0; n < 4; ++n) bv[n] = *(const bf16x8*)(lds + bA[kk][n] + bo);
      // swapped operands: D^T fragment -> lane holds 4 consecutive z-cols
#pragma unroll
      for (int m = 0; m < 4; ++m)
#pragma unroll
        for (int n = 0; n < 4; ++n)
          acc[m][n] = __builtin_amdgcn_mfma_f32_16x16x32_bf16(bv[n], av[m], acc[m][n], 0, 0, 0);
    }
  }
  // epilogue: D'[i][j]: i=(kg*4+reg) = W1-row (z-col), j=lr = x-row (z-row).
#pragma unroll
  for (int m = 0; m < 4; ++m) {
    const u32 zr = (u32)(rowBase + wm * 64 + m * 16 + lr);
#pragma unroll
    for (int n = 0; n < 4; ++n) {
      const int zc = wn * 64 + n * 16 + kg * 4;
      uint2 o;
      o.x = packbf2(acc[m][n][0], acc[m][n][1]);
      o.y = packbf2(acc[m][n][2], acc[m][n][3]);
      *(uint2*)(z + zr * DD + zc) = o;
    }
  }
}

// ---------------------------------------------------------------- K2
// h1 = leaky((z[neigh1].sum + z)/6). 8 rows/block, 32 lanes/row.
__global__ __launch_bounds__(256) void k2_agg1(
    const u16* __restrict__ z, const int* __restrict__ neigh1, u16* __restrict__ h1)
{
  const int t = threadIdx.x;
  const int row = blockIdx.x * 8 + (t >> 5);
  const int ch = t & 31;
  const u32 o0 = (u32)row * DD + ch * 8;
  uint4 a = *(const uint4*)(z + o0);
  float2 s0 = bf2f(a.x), s1 = bf2f(a.y), s2 = bf2f(a.z), s3 = bf2f(a.w);
#pragma unroll
  for (int j = 0; j < 5; ++j) {
    const int idx = neigh1[row * 5 + j];
    const uint4 v = *(const uint4*)(z + (u32)idx * DD + ch * 8);
    s0.x += bf_lo(v.x); s0.y += bf_hi(v.x);
    s1.x += bf_lo(v.y); s1.y += bf_hi(v.y);
    s2.x += bf_lo(v.z); s2.y += bf_hi(v.z);
    s3.x += bf_lo(v.w); s3.y += bf_hi(v.w);
  }
  const float sc = 1.0f / 6.0f;
  uint4 o;
  o.x = packbf2(lrelu(s0.x * sc), lrelu(s0.y * sc));
  o.y = packbf2(lrelu(s1.x * sc), lrelu(s1.y * sc));
  o.z = packbf2(lrelu(s2.x * sc), lrelu(s2.y * sc));
  o.w = packbf2(lrelu(s3.x * sc), lrelu(s3.y * sc));
  *(uint4*)(h1 + o0) = o;
}

// ---------------------------------------------------------------- K3 (fused layer2 + scores)
// h2tile = leaky(agg2 @ W2^T) kept in LDS; out = h2tile @ Wc^T.
// BM=64, BN=256, BK=64, 512 thr = 8 waves (2Mx4N), wave 32x64.
__global__ __launch_bounds__(512, 2) void k3_fused(
    const u16* __restrict__ h1, const u16* __restrict__ w2b, const u16* __restrict__ wcb,
    const int* __restrict__ nodes, const int* __restrict__ neigh2, float* __restrict__ out)
{
  // 0: A 8KB | 8192: B 32KB | 40960: Wc 24KB. After loop: 0..32KB = h2 tile.
  __shared__ __align__(16) unsigned char lds[65536];

  const int t = threadIdx.x;
  const int rowBase = blockIdx.x * 64;
  const int lane = t & 63, w = t >> 6;
  const int wm = w >> 2, wn = w & 3;
  const int lr = lane & 15, kg = lane >> 4;

  // Wc -> LDS once (pre-swizzled storage => linear copy). 48 rows (8 zero-pad).
#pragma unroll
  for (int i = 0; i < 3; ++i) {
    const int id = t + i * 512;
    uint4 v = make_uint4(0u, 0u, 0u, 0u);
    if (id < 1280) v = *(const uint4*)(wcb + (u32)id * 8);
    *(uint4*)(lds + 40960 + id * 16) = v;
  }

  // A gather: 1 chunk-task/thread (64 rows x 8 chunks), 11-way gather.
  const int r = t >> 3, c = t & 7;
  const int b = rowBase + r;
  u32 offA[11];
  offA[0] = (u32)nodes[b] * DD + (u32)c * 8;
#pragma unroll
  for (int j = 0; j < 10; ++j)
    offA[1 + j] = (u32)neigh2[b * 10 + j] * DD + (u32)c * 8;
  const int aW = swz(r, c);

  const u32 bofs = (u32)(w * 8 + (lane >> 3)) * DD + (u32)(lane & 7) * 8;
  unsigned char* bl0 = lds + 8192 + w * 1024;

  int aA[2][2], bA[2][4];
#pragma unroll
  for (int kk = 0; kk < 2; ++kk) {
    const int cb = kk * 4 + kg;
#pragma unroll
    for (int m = 0; m < 2; ++m) aA[kk][m] = swz(wm * 32 + m * 16 + lr, cb);
#pragma unroll
    for (int n = 0; n < 4; ++n) bA[kk][n] = 8192 + swz(wn * 64 + n * 16 + lr, cb);
  }

  f32x4 acc[2][4];
#pragma unroll
  for (int m = 0; m < 2; ++m)
#pragma unroll
    for (int n = 0; n < 4; ++n) acc[m][n] = (f32x4)0.0f;

  uint4 ag[11];
#pragma unroll
  for (int j = 0; j < 11; ++j) ag[j] = *(const uint4*)(h1 + offA[j]);

  for (int ks = 0; ks < 4; ++ks) {
    if (ks) __builtin_amdgcn_s_barrier();
    {
      float2 s0 = make_float2(0.f, 0.f), s1 = make_float2(0.f, 0.f);
      float2 s2 = make_float2(0.f, 0.f), s3 = make_float2(0.f, 0.f);
#pragma unroll
      for (int j = 0; j < 11; ++j) {
        s0.x += bf_lo(ag[j].x); s0.y += bf_hi(ag[j].x);
        s1.x += bf_lo(ag[j].y); s1.y += bf_hi(ag[j].y);
        s2.x += bf_lo(ag[j].z); s2.y += bf_hi(ag[j].z);
        s3.x += bf_lo(ag[j].w); s3.y += bf_hi(ag[j].w);
      }
      const float sc = 1.0f / 11.0f;
      uint4 o;
      o.x = packbf2(s0.x * sc, s0.y * sc);
      o.y = packbf2(s1.x * sc, s1.y * sc);
      o.z = packbf2(s2.x * sc, s2.y * sc);
      o.w = packbf2(s3.x * sc, s3.y * sc);
      *(uint4*)(lds + aW) = o;
    }
#pragma unroll
    for (int i = 0; i < 4; ++i)
      gld_lds16(w2b + bofs + (u32)i * 64 * DD + (u32)ks * 64, bl0 + i * 8192);
    __syncthreads();
    if (ks < 3) {
#pragma unroll
      for (int j = 0; j < 11; ++j)
        ag[j] = *(const uint4*)(h1 + offA[j] + (u32)(ks + 1) * 64);
    }
    __builtin_amdgcn_sched_barrier(0);
#pragma unroll
    for (int kk = 0; kk < 2; ++kk) {
      bf16x8 av[2], bv[4];
#pragma unroll
      for (int m = 0; m < 2; ++m) av[m] = *(const bf16x8*)(lds + aA[kk][m]);
#pragma unroll
      for (int n = 0; n < 4; ++n) bv[n] = *(const bf16x8*)(lds + bA[kk][n]);
#pragma unroll
      for (int m = 0; m < 2; ++m)
#pragma unroll
        for (int n = 0; n < 4; ++n)
          acc[m][n] = __builtin_amdgcn_mfma_f32_16x16x32_bf16(av[m], bv[n], acc[m][n], 0, 0, 0);
    }
  }

  __syncthreads();  // all waves done reading A/B before h2tile overwrites them
  // h2 tile -> LDS [64][256] bf16, swizzle: chunk low-3 bits ^= row&7
#pragma unroll
  for (int m = 0; m < 2; ++m) {
#pragma unroll
    for (int j = 0; j < 4; ++j) {
      const int row = wm * 32 + m * 16 + kg * 4 + j;
#pragma unroll
      for (int n = 0; n < 4; ++n) {
        const int col = wn * 64 + n * 16 + lr;
        const int ch = col >> 3;
        const int pch = (ch & 24) | ((ch ^ row) & 7);
        *(u16*)(lds + row * 512 + pch * 16 + (col & 7) * 2) = fbits(lrelu(acc[m][n][j]));
      }
    }
  }
  __syncthreads();

  if (w < 4) {  // scores: wave w -> output rows w*16..+15, 48 cols (40 valid)
    f32x4 acc2[3];
#pragma unroll
    for (int n = 0; n < 3; ++n) acc2[n] = (f32x4)0.0f;
    const int arow = w * 16 + lr;
#pragma unroll
    for (int ks2 = 0; ks2 < 8; ++ks2) {
      const int chb = ks2 * 4 + kg;
      const int pchA = (chb & 24) | ((chb ^ arow) & 7);
      const bf16x8 a = *(const bf16x8*)(lds + arow * 512 + pchA * 16);
#pragma unroll
      for (int n = 0; n < 3; ++n) {
        const int brow = n * 16 + lr;
        const int pchB = (chb & 24) | ((chb ^ brow) & 7);
        const bf16x8 bb = *(const bf16x8*)(lds + 40960 + brow * 512 + pchB * 16);
        acc2[n] = __builtin_amdgcn_mfma_f32_16x16x32_bf16(a, bb, acc2[n], 0, 0, 0);
      }
    }
#pragma unroll
    for (int n = 0; n < 3; ++n) {
      const int col = n * 16 + lr;
      if (col < CC) {
#pragma unroll
        for (int j = 0; j < 4; ++j) {
          const int rr = rowBase + w * 16 + kg * 4 + j;
          out[(u32)rr * CC + col] = acc2[n][j];
        }
      }
    }
  }
}

extern "C" void kernel_launch(void* const* d_in, const int* in_sizes, int n_in,
                              void* d_out, int out_size, void* d_ws, size_t ws_size,
                              hipStream_t stream) {
  const float* x    = (const float*)d_in[0];
  const float* W1   = (const float*)d_in[1];
  const float* W2   = (const float*)d_in[2];
  const float* Wc   = (const float*)d_in[3];
  const int* nodes  = (const int*)d_in[4];
  const int* neigh1 = (const int*)d_in[5];
  const int* neigh2 = (const int*)d_in[6];

  u16* z   = (u16*)d_ws;                     // 100096*256 bf16
  u16* h1  = z + (size_t)100096 * 256;       // 100096*256 bf16
  u16* w1b = h1 + (size_t)100096 * 256;      // 256x512 bf16 (chunk-swizzled)
  u16* w2b = w1b + (size_t)256 * 512;        // 256x256 bf16 (chunk-swizzled)
  u16* wcb = w2b + (size_t)256 * 256;        // 40x256 bf16 (chunk-swizzled)

  k0_cvt<<<dim3(101), dim3(256), 0, stream>>>(W1, W2, Wc, w1b, w2b, wcb);
  k1_gemm<<<dim3(782), dim3(512), 0, stream>>>(x, w1b, z);
  k2_agg1<<<dim3(12500), dim3(256), 0, stream>>>(z, neigh1, h1);
  k3_fused<<<dim3(256), dim3(512), 0, stream>>>(h1, w2b, wcb, nodes, neigh2, (float*)d_out);
}

// Round 5
// 151.218 us; speedup vs baseline: 1.0417x; 1.0057x over previous
//
#include <hip/hip_runtime.h>
#include <hip/hip_bf16.h>

// SupervisedGraphSage forward. fp32 device buffers; bf16 MFMA internally.
//   z  = x @ W1^T                        [N, D]  (K1, nt-loads for x)
//   h1 = leaky((z[neigh1].sum + z)/6)    [N, D]  (K2, only referenced rows)
//   h2 = leaky((h1[neigh2].sum+h1[nodes])/11 @ W2^T); out = h2 @ Wc^T  (K3 fused)
// x is streamed with nontemporal loads so the 51 MB z buffer stays L3-resident
// for K2's 6-way random gather (x:205MB + z:51MB == L3 capacity otherwise).

#define NN 100000
#define FF 512
#define DD 256
#define BB 16384
#define CC 40

typedef __attribute__((ext_vector_type(8))) short bf16x8;
typedef __attribute__((ext_vector_type(4))) float f32x4;
typedef unsigned short u16;
typedef unsigned int u32;
typedef __attribute__((ext_vector_type(4))) u32 u32x4;

__device__ __forceinline__ float bf_lo(u32 u) { u32 v = u << 16; float f; __builtin_memcpy(&f, &v, 4); return f; }
__device__ __forceinline__ float bf_hi(u32 u) { u32 v = u & 0xffff0000u; float f; __builtin_memcpy(&f, &v, 4); return f; }
__device__ __forceinline__ float2 bf2f(u32 u) { return make_float2(bf_lo(u), bf_hi(u)); }
__device__ __forceinline__ float asf(u32 u) { float f; __builtin_memcpy(&f, &u, 4); return f; }
__device__ __forceinline__ u32 packbf2(float a, float b) {
  __hip_bfloat162 h = __float22bfloat162_rn(make_float2(a, b));
  u32 u; __builtin_memcpy(&u, &h, 4); return u;
}
__device__ __forceinline__ u16 fbits(float v) {
  __hip_bfloat16 h = __float2bfloat16(v);
  u16 u; __builtin_memcpy(&u, &h, 2); return u;
}
__device__ __forceinline__ float lrelu(float v) { return v >= 0.f ? v : 0.2f * v; }
// [R][64]-bf16 tile: byte offset of chunk c in row r, XOR-swizzled (G4).
__device__ __forceinline__ int swz(int r, int c) { return r * 128 + ((c ^ (r & 7)) << 4); }
// direct global->LDS 16B copy (dest = wave-uniform base + lane*16)
__device__ __forceinline__ void gld_lds16(const u16* g, void* l) {
  __builtin_amdgcn_global_load_lds((const __attribute__((address_space(1))) unsigned int*)g,
                                   (__attribute__((address_space(3))) unsigned int*)l, 16, 0, 0);
}
// nontemporal 16B load (x streamed once; don't let it evict z from L3)
__device__ __forceinline__ u32x4 nt4(const float* p) {
  return __builtin_nontemporal_load((const u32x4*)p);
}

// ---------------------------------------------------------------- K0
// fp32 weights -> bf16, chunk-swizzled storage; also zero the h1-row flags.
__global__ __launch_bounds__(256) void k0_cvt(
    const float* __restrict__ W1, const float* __restrict__ W2, const float* __restrict__ Wc,
    u16* __restrict__ w1b, u16* __restrict__ w2b, u16* __restrict__ wcb,
    u32* __restrict__ flagw)
{
  const int i = blockIdx.x * 256 + threadIdx.x;
  if (i < 25024) flagw[i] = 0;   // 100096 flag bytes
  const float* src; u16* dst; int r, cc, rowE;
  if (i < 16384)      { src = W1; dst = w1b; r = i >> 6; cc = i & 63; rowE = 512; }
  else if (i < 24576) { int j = i - 16384; src = W2; dst = w2b; r = j >> 5; cc = j & 31; rowE = 256; }
  else if (i < 25856) { int j = i - 24576; src = Wc; dst = wcb; r = j >> 5; cc = j & 31; rowE = 256; }
  else return;
  const int g = cc >> 3, cp = cc & 7;
  const float* s = src + (u32)r * rowE + g * 64 + (u32)(cp ^ (r & 7)) * 8;
  const float4 v0 = *(const float4*)s;
  const float4 v1 = *(const float4*)(s + 4);
  uint4 o;
  o.x = packbf2(v0.x, v0.y); o.y = packbf2(v0.z, v0.w);
  o.z = packbf2(v1.x, v1.y); o.w = packbf2(v1.z, v1.w);
  *(uint4*)(dst + (u32)r * rowE + g * 64 + cp * 8) = o;
}

// ---------------------------------------------------------------- K0b
// Mark h1 rows actually consumed by layer 2 (nodes + neigh2).
__global__ __launch_bounds__(256) void k0b_flags(
    const int* __restrict__ nodes, const int* __restrict__ neigh2,
    unsigned char* __restrict__ flags)
{
  const int i = blockIdx.x * 256 + threadIdx.x;
  int idx;
  if (i < BB) idx = nodes[i];
  else if (i < BB + BB * 10) idx = neigh2[i - BB];
  else return;
  flags[idx] = 1;
}

// ---------------------------------------------------------------- K1
// z = x @ W1^T. BM=128, BN=256, BK=64, 512 thr = 8 waves (2Mx4N), wave 64x64.
// A: fp32->bf16 reg-staged (nt-prefetched). B: global_load_lds into 2 LDS bufs,
// counted vmcnt(8). Swapped-operand MFMA -> 8B-contiguous epilogue stores.
__global__ __launch_bounds__(512, 4) void k1_gemm(
    const float* __restrict__ x, const u16* __restrict__ w1b, u16* __restrict__ z)
{
  __shared__ __align__(16) unsigned char lds[81920];  // A 16KB @0, B0 @16384, B1 @49152

  const int t = threadIdx.x;
  const int rowBase = blockIdx.x * 128;
  const int lane = t & 63, w = t >> 6;
  const int wm = w >> 2, wn = w & 3;
  const int lr = lane & 15, kg = lane >> 4;

  u32 offA[2]; int aW[2];
#pragma unroll
  for (int i = 0; i < 2; ++i) {
    const int id = t + i * 512;
    const int r = id >> 3, c = id & 7;
    int row = rowBase + r; if (row > NN - 1) row = NN - 1;
    offA[i] = (u32)row * FF + c * 8;
    aW[i] = swz(r, c);
  }
  const u32 bofs = (u32)(w * 8 + (lane >> 3)) * FF + (u32)(lane & 7) * 8;

  int aA[2][4], bA[2][4];
#pragma unroll
  for (int kk = 0; kk < 2; ++kk) {
    const int cb = kk * 4 + kg;
#pragma unroll
    for (int m = 0; m < 4; ++m) aA[kk][m] = swz(wm * 64 + m * 16 + lr, cb);
#pragma unroll
    for (int n = 0; n < 4; ++n) bA[kk][n] = 16384 + swz(wn * 64 + n * 16 + lr, cb);
  }

  f32x4 acc[4][4];
#pragma unroll
  for (int m = 0; m < 4; ++m)
#pragma unroll
    for (int n = 0; n < 4; ++n) acc[m][n] = (f32x4)0.0f;

  u32x4 pa[2][2];
#pragma unroll
  for (int i = 0; i < 2; ++i) {
    pa[i][0] = nt4(x + offA[i]);
    pa[i][1] = nt4(x + offA[i] + 4);
  }
#pragma unroll
  for (int i = 0; i < 4; ++i)
    gld_lds16(w1b + bofs + (u32)i * 64 * FF, lds + 16384 + w * 1024 + i * 8192);

#pragma unroll
  for (int ks = 0; ks < 8; ++ks) {
    if (ks) {
      __builtin_amdgcn_s_barrier();
      __builtin_amdgcn_sched_barrier(0);
    }
#pragma unroll
    for (int i = 0; i < 2; ++i) {
      uint4 o;
      o.x = packbf2(asf(pa[i][0][0]), asf(pa[i][0][1]));
      o.y = packbf2(asf(pa[i][0][2]), asf(pa[i][0][3]));
      o.z = packbf2(asf(pa[i][1][0]), asf(pa[i][1][1]));
      o.w = packbf2(asf(pa[i][1][2]), asf(pa[i][1][3]));
      *(uint4*)(lds + aW[i]) = o;
    }
    if (ks < 7) {
#pragma unroll
      for (int i = 0; i < 2; ++i) {
        pa[i][0] = nt4(x + offA[i] + (u32)(ks + 1) * 64);
        pa[i][1] = nt4(x + offA[i] + (u32)(ks + 1) * 64 + 4);
      }
      unsigned char* bl = lds + 16384 + ((ks + 1) & 1) * 32768 + w * 1024;
#pragma unroll
      for (int i = 0; i < 4; ++i)
        gld_lds16(w1b + bofs + (u32)i * 64 * FF + (u32)(ks + 1) * 64, bl + i * 8192);
      asm volatile("s_waitcnt vmcnt(8) lgkmcnt(0)" ::: "memory");  // B[ks] landed
    } else {
      asm volatile("s_waitcnt vmcnt(0) lgkmcnt(0)" ::: "memory");
    }
    __builtin_amdgcn_sched_barrier(0);
    __builtin_amdgcn_s_barrier();
    __builtin_amdgcn_sched_barrier(0);
    const int bo = (ks & 1) * 32768;
#pragma unroll
    for (int kk = 0; kk < 2; ++kk) {
      bf16x8 av[4], bv[4];
#pragma unroll
      for (int m = 0; m < 4; ++m) av[m] = *(const bf16x8*)(lds + aA[kk][m]);
#pragma unroll
      for (int n = 0; n < 4; ++n) bv[n] = *(const bf16x8*)(lds + bA[kk][n] + bo);
#pragma unroll
      for (int m = 0; m < 4; ++m)
#pragma unroll
        for (int n = 0; n < 4; ++n)
          acc[m][n] = __builtin_amdgcn_mfma_f32_16x16x32_bf16(bv[n], av[m], acc[m][n], 0, 0, 0);
    }
  }
  // epilogue: swapped D -> lane holds 4 consecutive z-cols of one z-row.
#pragma unroll
  for (int m = 0; m < 4; ++m) {
    const u32 zr = (u32)(rowBase + wm * 64 + m * 16 + lr);
#pragma unroll
    for (int n = 0; n < 4; ++n) {
      const int zc = wn * 64 + n * 16 + kg * 4;
      uint2 o;
      o.x = packbf2(acc[m][n][0], acc[m][n][1]);
      o.y = packbf2(acc[m][n][2], acc[m][n][3]);
      *(uint2*)(z + zr * DD + zc) = o;
    }
  }
}

// ---------------------------------------------------------------- K2
// h1 = leaky((z[neigh1].sum + z)/6), only for rows layer 2 reads.
__global__ __launch_bounds__(256) void k2_agg1(
    const u16* __restrict__ z, const int* __restrict__ neigh1, u16* __restrict__ h1,
    const unsigned char* __restrict__ flags)
{
  const int t = threadIdx.x;
  const int row = blockIdx.x * 8 + (t >> 5);
  if (!flags[row]) return;   // half-wave uniform; no barriers in this kernel
  const int ch = t & 31;
  const u32 o0 = (u32)row * DD + ch * 8;
  uint4 a = *(const uint4*)(z + o0);
  float2 s0 = bf2f(a.x), s1 = bf2f(a.y), s2 = bf2f(a.z), s3 = bf2f(a.w);
#pragma unroll
  for (int j = 0; j < 5; ++j) {
    const int idx = neigh1[row * 5 + j];
    const uint4 v = *(const uint4*)(z + (u32)idx * DD + ch * 8);
    s0.x += bf_lo(v.x); s0.y += bf_hi(v.x);
    s1.x += bf_lo(v.y); s1.y += bf_hi(v.y);
    s2.x += bf_lo(v.z); s2.y += bf_hi(v.z);
    s3.x += bf_lo(v.w); s3.y += bf_hi(v.w);
  }
  const float sc = 1.0f / 6.0f;
  uint4 o;
  o.x = packbf2(lrelu(s0.x * sc), lrelu(s0.y * sc));
  o.y = packbf2(lrelu(s1.x * sc), lrelu(s1.y * sc));
  o.z = packbf2(lrelu(s2.x * sc), lrelu(s2.y * sc));
  o.w = packbf2(lrelu(s3.x * sc), lrelu(s3.y * sc));
  *(uint4*)(h1 + o0) = o;
}

// ---------------------------------------------------------------- K3 (fused layer2 + scores)
// h2tile = leaky(agg2 @ W2^T) kept in LDS; out = h2tile @ Wc^T.
// BM=64, BN=256, BK=64, 512 thr = 8 waves (2Mx4N), wave 32x64.
__global__ __launch_bounds__(512, 2) void k3_fused(
    const u16* __restrict__ h1, const u16* __restrict__ w2b, const u16* __restrict__ wcb,
    const int* __restrict__ nodes, const int* __restrict__ neigh2, float* __restrict__ out)
{
  // 0: A 8KB | 8192: B 32KB | 40960: Wc 24KB. After loop: 0..32KB = h2 tile.
  __shared__ __align__(16) unsigned char lds[65536];

  const int t = threadIdx.x;
  const int rowBase = blockIdx.x * 64;
  const int lane = t & 63, w = t >> 6;
  const int wm = w >> 2, wn = w & 3;
  const int lr = lane & 15, kg = lane >> 4;

#pragma unroll
  for (int i = 0; i < 3; ++i) {
    const int id = t + i * 512;
    uint4 v = make_uint4(0u, 0u, 0u, 0u);
    if (id < 1280) v = *(const uint4*)(wcb + (u32)id * 8);
    *(uint4*)(lds + 40960 + id * 16) = v;
  }

  const int r = t >> 3, c = t & 7;
  const int b = rowBase + r;
  u32 offA[11];
  offA[0] = (u32)nodes[b] * DD + (u32)c * 8;
#pragma unroll
  for (int j = 0; j < 10; ++j)
    offA[1 + j] = (u32)neigh2[b * 10 + j] * DD + (u32)c * 8;
  const int aW = swz(r, c);

  const u32 bofs = (u32)(w * 8 + (lane >> 3)) * DD + (u32)(lane & 7) * 8;
  unsigned char* bl0 = lds + 8192 + w * 1024;

  int aA[2][2], bA[2][4];
#pragma unroll
  for (int kk = 0; kk < 2; ++kk) {
    const int cb = kk * 4 + kg;
#pragma unroll
    for (int m = 0; m < 2; ++m) aA[kk][m] = swz(wm * 32 + m * 16 + lr, cb);
#pragma unroll
    for (int n = 0; n < 4; ++n) bA[kk][n] = 8192 + swz(wn * 64 + n * 16 + lr, cb);
  }

  f32x4 acc[2][4];
#pragma unroll
  for (int m = 0; m < 2; ++m)
#pragma unroll
    for (int n = 0; n < 4; ++n) acc[m][n] = (f32x4)0.0f;

  uint4 ag[11];
#pragma unroll
  for (int j = 0; j < 11; ++j) ag[j] = *(const uint4*)(h1 + offA[j]);

  for (int ks = 0; ks < 4; ++ks) {
    if (ks) __builtin_amdgcn_s_barrier();
    {
      float2 s0 = make_float2(0.f, 0.f), s1 = make_float2(0.f, 0.f);
      float2 s2 = make_float2(0.f, 0.f), s3 = make_float2(0.f, 0.f);
#pragma unroll
      for (int j = 0; j < 11; ++j) {
        s0.x += bf_lo(ag[j].x); s0.y += bf_hi(ag[j].x);
        s1.x += bf_lo(ag[j].y); s1.y += bf_hi(ag[j].y);
        s2.x += bf_lo(ag[j].z); s2.y += bf_hi(ag[j].z);
        s3.x += bf_lo(ag[j].w); s3.y += bf_hi(ag[j].w);
      }
      const float sc = 1.0f / 11.0f;
      uint4 o;
      o.x = packbf2(s0.x * sc, s0.y * sc);
      o.y = packbf2(s1.x * sc, s1.y * sc);
      o.z = packbf2(s2.x * sc, s2.y * sc);
      o.w = packbf2(s3.x * sc, s3.y * sc);
      *(uint4*)(lds + aW) = o;
    }
#pragma unroll
    for (int i = 0; i < 4; ++i)
      gld_lds16(w2b + bofs + (u32)i * 64 * DD + (u32)ks * 64, bl0 + i * 8192);
    __syncthreads();
    if (ks < 3) {
#pragma unroll
      for (int j = 0; j < 11; ++j)
        ag[j] = *(const uint4*)(h1 + offA[j] + (u32)(ks + 1) * 64);
    }
    __builtin_amdgcn_sched_barrier(0);
#pragma unroll
    for (int kk = 0; kk < 2; ++kk) {
      bf16x8 av[2], bv[4];
#pragma unroll
      for (int m = 0; m < 2; ++m) av[m] = *(const bf16x8*)(lds + aA[kk][m]);
#pragma unroll
      for (int n = 0; n < 4; ++n) bv[n] = *(const bf16x8*)(lds + bA[kk][n]);
#pragma unroll
      for (int m = 0; m < 2; ++m)
#pragma unroll
        for (int n = 0; n < 4; ++n)
          acc[m][n] = __builtin_amdgcn_mfma_f32_16x16x32_bf16(av[m], bv[n], acc[m][n], 0, 0, 0);
    }
  }

  __syncthreads();
#pragma unroll
  for (int m = 0; m < 2; ++m) {
#pragma unroll
    for (int j = 0; j < 4; ++j) {
      const int row = wm * 32 + m * 16 + kg * 4 + j;
#pragma unroll
      for (int n = 0; n < 4; ++n) {
        const int col = wn * 64 + n * 16 + lr;
        const int ch = col >> 3;
        const int pch = (ch & 24) | ((ch ^ row) & 7);
        *(u16*)(lds + row * 512 + pch * 16 + (col & 7) * 2) = fbits(lrelu(acc[m][n][j]));
      }
    }
  }
  __syncthreads();

  if (w < 4) {
    f32x4 acc2[3];
#pragma unroll
    for (int n = 0; n < 3; ++n) acc2[n] = (f32x4)0.0f;
    const int arow = w * 16 + lr;
#pragma unroll
    for (int ks2 = 0; ks2 < 8; ++ks2) {
      const int chb = ks2 * 4 + kg;
      const int pchA = (chb & 24) | ((chb ^ arow) & 7);
      const bf16x8 a = *(const bf16x8*)(lds + arow * 512 + pchA * 16);
#pragma unroll
      for (int n = 0; n < 3; ++n) {
        const int brow = n * 16 + lr;
        const int pchB = (chb & 24) | ((chb ^ brow) & 7);
        const bf16x8 bb = *(const bf16x8*)(lds + 40960 + brow * 512 + pchB * 16);
        acc2[n] = __builtin_amdgcn_mfma_f32_16x16x32_bf16(a, bb, acc2[n], 0, 0, 0);
      }
    }
#pragma unroll
    for (int n = 0; n < 3; ++n) {
      const int col = n * 16 + lr;
      if (col < CC) {
#pragma unroll
        for (int j = 0; j < 4; ++j) {
          const int rr = rowBase + w * 16 + kg * 4 + j;
          out[(u32)rr * CC + col] = acc2[n][j];
        }
      }
    }
  }
}

extern "C" void kernel_launch(void* const* d_in, const int* in_sizes, int n_in,
                              void* d_out, int out_size, void* d_ws, size_t ws_size,
                              hipStream_t stream) {
  const float* x    = (const float*)d_in[0];
  const float* W1   = (const float*)d_in[1];
  const float* W2   = (const float*)d_in[2];
  const float* Wc   = (const float*)d_in[3];
  const int* nodes  = (const int*)d_in[4];
  const int* neigh1 = (const int*)d_in[5];
  const int* neigh2 = (const int*)d_in[6];

  u16* z   = (u16*)d_ws;                     // 100096*256 bf16
  u16* h1  = z + (size_t)100096 * 256;       // 100096*256 bf16
  u16* w1b = h1 + (size_t)100096 * 256;      // 256x512 bf16 (chunk-swizzled)
  u16* w2b = w1b + (size_t)256 * 512;        // 256x256 bf16 (chunk-swizzled)
  u16* wcb = w2b + (size_t)256 * 256;        // 40x256 bf16 (chunk-swizzled)
  u32* flagw = (u32*)(wcb + (size_t)40 * 256);  // 25024 u32 = 100096 flag bytes
  unsigned char* flags = (unsigned char*)flagw;

  k0_cvt<<<dim3(101), dim3(256), 0, stream>>>(W1, W2, Wc, w1b, w2b, wcb, flagw);
  k0b_flags<<<dim3(704), dim3(256), 0, stream>>>(nodes, neigh2, flags);
  k1_gemm<<<dim3(782), dim3(512), 0, stream>>>(x, w1b, z);
  k2_agg1<<<dim3(12500), dim3(256), 0, stream>>>(z, neigh1, h1, flags);
  k3_fused<<<dim3(256), dim3(512), 0, stream>>>(h1, w2b, wcb, nodes, neigh2, (float*)d_out);
}